// Round 6
// baseline (826.524 us; speedup 1.0000x reference)
//
#include <hip/hip_runtime.h>
#include <math.h>

#define Bn 32
#define Nn 256
#define IDIM 2048
#define PDIM 768
#define VDIM 1024
#define SDIM 8
#define D2 2816
#define Mrows 8192
#define EPSN 1e-8f
#define LNEPS 1e-5f
#define THRESH 0.5f

typedef unsigned short u16;
typedef unsigned long long u64;
typedef __attribute__((ext_vector_type(8))) short bf16x8;
typedef __attribute__((ext_vector_type(4))) float f32x4;

// fp32 -> bf16 round-to-nearest-even
__device__ __forceinline__ u16 f2b(float f) {
    unsigned u = __float_as_uint(f);
    unsigned r = (u + 0x7FFFu + ((u >> 16) & 1u)) >> 16;
    return (u16)r;
}

__device__ __forceinline__ void gload16(const void* g, void* l) {
    __builtin_amdgcn_global_load_lds(
        (const __attribute__((address_space(1))) unsigned*)g,
        (__attribute__((address_space(3))) unsigned*)l, 16, 0, 0);
}

#define VMWAIT4 asm volatile("s_waitcnt vmcnt(4)" ::: "memory")
#define VMWAIT2 asm volatile("s_waitcnt vmcnt(2)" ::: "memory")
#define VMWAIT0 asm volatile("s_waitcnt vmcnt(0)" ::: "memory")
#define LGKM8   asm volatile("s_waitcnt lgkmcnt(8)" ::: "memory")
#define BAR() do { __builtin_amdgcn_s_barrier(); __builtin_amdgcn_sched_barrier(0); } while (0)
#define PRIO1 __builtin_amdgcn_s_setprio(1)
#define PRIO0 __builtin_amdgcn_s_setprio(0)

// ---------------------------------------------------------------------------
// pack: fp32 image/pc -> bf16 concat rows [8192][2816], plus row L2 norms.
// ---------------------------------------------------------------------------
__global__ __launch_bounds__(256) void pack_k(
    const float* __restrict__ img, const float* __restrict__ pc,
    const float* __restrict__ pimg, const float* __restrict__ ppc,
    u16* __restrict__ featb, u16* __restrict__ pfeatb,
    float* __restrict__ nf, float* __restrict__ np_)
{
    const int row = blockIdx.x, t = threadIdx.x;
    const float* I = blockIdx.y ? pimg : img;
    const float* P = blockIdx.y ? ppc : pc;
    u16* O = blockIdx.y ? pfeatb : featb;
    float s = 0.f;
    const float4* I4 = (const float4*)(I + (size_t)row * IDIM);
    float4 a = I4[t * 2], b = I4[t * 2 + 1];
    s += a.x * a.x + a.y * a.y + a.z * a.z + a.w * a.w;
    s += b.x * b.x + b.y * b.y + b.z * b.z + b.w * b.w;
    u16* op = O + (size_t)row * D2 + t * 8;
    *(ushort4*)op       = make_ushort4(f2b(a.x), f2b(a.y), f2b(a.z), f2b(a.w));
    *(ushort4*)(op + 4) = make_ushort4(f2b(b.x), f2b(b.y), f2b(b.z), f2b(b.w));
    if (t < 192) {
        float4 c = ((const float4*)(P + (size_t)row * PDIM))[t];
        s += c.x * c.x + c.y * c.y + c.z * c.z + c.w * c.w;
        *(ushort4*)(O + (size_t)row * D2 + IDIM + t * 4) =
            make_ushort4(f2b(c.x), f2b(c.y), f2b(c.z), f2b(c.w));
    }
    for (int o = 32; o; o >>= 1) s += __shfl_down(s, o, 64);
    __shared__ float l4[4];
    if ((t & 63) == 0) l4[t >> 6] = s;
    __syncthreads();
    if (t == 0) (blockIdx.y ? np_ : nf)[row] = sqrtf(l4[0] + l4[1] + l4[2] + l4[3]);
}

// ---------------------------------------------------------------------------
// grouped weight transpose: 8 weights, W[K][No] fp32 -> Wt[No][K] bf16.
// ---------------------------------------------------------------------------
struct TD { const float* W; u16* Wt; int K, No, blk0; };

__global__ __launch_bounds__(256) void twtg_k(
    TD a0, TD a1, TD a2, TD a3, TD a4, TD a5, TD a6, TD a7)
{
    const int bid = blockIdx.x;
    TD d;
    if      (bid >= a7.blk0) d = a7;
    else if (bid >= a6.blk0) d = a6;
    else if (bid >= a5.blk0) d = a5;
    else if (bid >= a4.blk0) d = a4;
    else if (bid >= a3.blk0) d = a3;
    else if (bid >= a2.blk0) d = a2;
    else if (bid >= a1.blk0) d = a1;
    else                     d = a0;
    const int local = bid - d.blk0;
    const int nx = d.No >> 5;
    const int n0 = (local % nx) * 32, k0 = (local / nx) * 32;

    __shared__ float tb[32][33];
    const int tx = threadIdx.x & 31;
    const int ty = threadIdx.x >> 5;
#pragma unroll
    for (int qq = 0; qq < 4; ++qq)
        tb[ty + 8 * qq][tx] = d.W[(size_t)(k0 + ty + 8 * qq) * d.No + n0 + tx];
    __syncthreads();
#pragma unroll
    for (int qq = 0; qq < 4; ++qq)
        d.Wt[(size_t)(n0 + ty + 8 * qq) * d.K + k0 + tx] = f2b(tb[tx][ty + 8 * qq]);
}

// ---------------------------------------------------------------------------
// simmm_k (128^2, round-2 structure): sim GEMM, normalized fp32 out.
// ---------------------------------------------------------------------------
__global__ __launch_bounds__(256) void simmm_k(
    const u16* __restrict__ A, const u16* __restrict__ Bt,
    const float* __restrict__ nf, const float* __restrict__ np_,
    float* __restrict__ Cout)
{
    __shared__ __align__(16) u16 Asm[4096];
    __shared__ __align__(16) u16 Bsm[4096];
    const int tid = threadIdx.x;
    const int wave = tid >> 6, lane = tid & 63;
    const int row0 = blockIdx.y * 128;
    const int cC0 = blockIdx.x * 128;
    const int brow0 = (row0 >> 8) * Nn + cC0;
    const int lda = D2, K = D2, ldc = Nn;

    const int la = lane >> 2, q = lane & 3;
    const u16* pA0[2]; const u16* pB0[2];
    char* dstA[2]; char* dstB[2];
#pragma unroll
    for (int i = 0; i < 2; ++i) {
        int c = wave * 2 + i;
        int r = c * 16 + la;
        int sp = q ^ ((r >> 1) & 3);
        pA0[i] = A + (size_t)(row0 + r) * lda + sp * 8;
        pB0[i] = Bt + (size_t)(brow0 + r) * K + sp * 8;
        dstA[i] = (char*)Asm + c * 1024;
        dstB[i] = (char*)Bsm + c * 1024;
    }

    const int wr = wave >> 1, wc = wave & 1;
    int aoff[4], boff[4];   // BYTE offsets
#pragma unroll
    for (int m = 0; m < 4; ++m) {
        int r = wr * 64 + m * 16 + (lane & 15);
        aoff[m] = r * 64 + (((lane >> 4) ^ ((r >> 1) & 3)) << 4);
    }
#pragma unroll
    for (int n = 0; n < 4; ++n) {
        int c = wc * 64 + n * 16 + (lane & 15);
        boff[n] = c * 64 + (((lane >> 4) ^ ((c >> 1) & 3)) << 4);
    }

    f32x4 acc[4][4] = {};
    for (int k0 = 0; k0 < K; k0 += 32) {
#pragma unroll
        for (int i = 0; i < 2; ++i) {
            gload16(pA0[i] + k0, dstA[i]);
            gload16(pB0[i] + k0, dstB[i]);
        }
        __syncthreads();
        bf16x8 av[4], bv[4];
#pragma unroll
        for (int m = 0; m < 4; ++m) av[m] = *(const bf16x8*)((const char*)Asm + aoff[m]);
#pragma unroll
        for (int n = 0; n < 4; ++n) bv[n] = *(const bf16x8*)((const char*)Bsm + boff[n]);
#pragma unroll
        for (int m = 0; m < 4; ++m)
#pragma unroll
            for (int n = 0; n < 4; ++n)
                acc[m][n] = __builtin_amdgcn_mfma_f32_16x16x32_bf16(av[m], bv[n], acc[m][n], 0, 0, 0);
        __syncthreads();
    }

    const int rb = row0 + wr * 64;
    const int cl = cC0 + wc * 64 + (lane & 15);
    float sj[4];
#pragma unroll
    for (int n = 0; n < 4; ++n)
        sj[n] = 1.f / fmaxf(np_[brow0 + wc * 64 + n * 16 + (lane & 15)], EPSN);
#pragma unroll
    for (int m = 0; m < 4; ++m)
#pragma unroll
        for (int n = 0; n < 4; ++n) {
            f32x4 v = acc[m][n];
#pragma unroll
            for (int rg = 0; rg < 4; ++rg) {
                int rr = rb + m * 16 + ((lane >> 4) << 2) + rg;
                float si = 1.f / fmaxf(nf[rr], EPSN);
                Cout[(size_t)rr * ldc + cl + n * 16] = v[rg] * si * sj[n];
            }
        }
}

// ---------------------------------------------------------------------------
// mmg_k: grouped 256x256 8-phase MFMA GEMM (two descriptor groups).
// Phase skeleton per m201 template: {READ frags; STAGE next; s_barrier;
// setprio(1) MFMA setprio(0); [vmcnt gate]; s_barrier}. Reads are issued
// BEFORE the barrier so LDS latency hides under the barrier wait and the
// MFMA region is pure-MFMA.
// ---------------------------------------------------------------------------
struct MMDesc {
    const u16* A; const u16* Aprev; const u16* zb; const int* midx;
    const u16* Bt; const float* bias; void* C;
    int lda, coff, K1, K, ldc, nwg;
};

template <int MODE, int RELU, int OUT>
__global__ __launch_bounds__(512, 2) void mmg_k(MMDesc da, MMDesc db, int split)
{
    __shared__ __align__(16) u16 smem[65536];   // 128 KiB
    char* ldsv = (char*)smem;

    const int bid = blockIdx.x;
    const MMDesc d = (bid < split) ? da : db;
    const int local = (bid < split) ? bid : (bid - split);

    const int tid = threadIdx.x;
    const int wave = tid >> 6, lane = tid & 63;
    const int l15 = lane & 15, l4 = lane >> 4;
    const int wr = wave >> 2, wc = wave & 3;

    // XCD-bijective swizzle within group
    const int nwg = d.nwg;
    const int xcd = local & 7, lid = local >> 3;
    const int qq = nwg >> 3, rr8 = nwg & 7;
    const int swz = (xcd < rr8 ? xcd * (qq + 1) : rr8 * (qq + 1) + (xcd - rr8) * qq) + lid;
    const int row0 = (swz & 31) * 256;
    const int col0 = (swz >> 5) * 256;

    const int K1 = d.K1, lda = d.lda, coff = d.coff, K = d.K;

    const u16* pA[2][2]; const u16* pA2[2][2]; const u16* pB[2][2];
    int cA8[2][2]; bool okA[2][2];
#pragma unroll
    for (int h = 0; h < 2; ++h)
#pragma unroll
        for (int i = 0; i < 2; ++i) {
            int lrow = (i * 512 + tid) >> 3;
            int r = h * 128 + lrow;
            int c = (tid & 7) ^ (lrow & 7);
            cA8[h][i] = c * 8;
            int grow = row0 + r;
            if (MODE == 0) {
                pA[h][i] = d.A + (size_t)grow * lda + c * 8;
                pA2[h][i] = nullptr; okA[h][i] = true;
            } else {
                pA[h][i] = d.A + (size_t)grow * lda + coff + c * 8;
                int jj = d.midx[grow];
                okA[h][i] = (jj >= 0);
                pA2[h][i] = okA[h][i]
                    ? (d.Aprev + (size_t)((grow & ~(Nn - 1)) + jj) * lda + coff + c * 8 - K1)
                    : (d.zb + c * 8);
            }
            pB[h][i] = d.Bt + (size_t)(col0 + r) * K + c * 8;
        }

#define STAGEA(h, kt, pp) do {                                                   \
    _Pragma("unroll")                                                            \
    for (int i_ = 0; i_ < 2; ++i_) {                                             \
        const u16* s_;                                                           \
        if (MODE == 0) s_ = pA[h][i_] + (kt);                                    \
        else {                                                                   \
            int gc_ = (kt) + cA8[h][i_];                                         \
            s_ = (gc_ < K1) ? (pA[h][i_] + (kt))                                 \
                            : (okA[h][i_] ? pA2[h][i_] + (kt) : pA2[h][i_]);     \
        }                                                                        \
        gload16(s_, ldsv + ((pp) * 32768 + (h) * 16384 + i_ * 8192 + wave * 1024)); \
    }                                                                            \
} while (0)

#define STAGEB(h, kt, pp) do {                                                   \
    _Pragma("unroll")                                                            \
    for (int i_ = 0; i_ < 2; ++i_)                                               \
        gload16(pB[h][i_] + (kt),                                                \
                ldsv + (65536 + (pp) * 32768 + (h) * 16384 + i_ * 8192 + wave * 1024)); \
} while (0)

    int aoffs[8][2], boffs[4][2];
#pragma unroll
    for (int m = 0; m < 8; ++m) {
        int r = m * 32 + wr * 16 + l15;
#pragma unroll
        for (int ks = 0; ks < 2; ++ks)
            aoffs[m][ks] = r * 128 + (((ks * 4 + l4) ^ (lane & 7)) << 4);
    }
#pragma unroll
    for (int n = 0; n < 4; ++n) {
        int r = n * 64 + wc * 16 + l15;
#pragma unroll
        for (int ks = 0; ks < 2; ++ks)
            boffs[n][ks] = r * 128 + (((ks * 4 + l4) ^ (lane & 7)) << 4);
    }

    bf16x8 avc[4][2], bvc[2][2];
    f32x4 acc[8][4] = {};

#define READA(mh, base) do {                                                     \
    _Pragma("unroll")                                                            \
    for (int m_ = 0; m_ < 4; ++m_) {                                             \
        avc[m_][0] = *(const bf16x8*)((base) + aoffs[(mh) * 4 + m_][0]);         \
        avc[m_][1] = *(const bf16x8*)((base) + aoffs[(mh) * 4 + m_][1]);         \
    }                                                                            \
} while (0)

#define READB(nh, base) do {                                                     \
    _Pragma("unroll")                                                            \
    for (int n_ = 0; n_ < 2; ++n_) {                                             \
        bvc[n_][0] = *(const bf16x8*)((base) + boffs[(nh) * 2 + n_][0]);         \
        bvc[n_][1] = *(const bf16x8*)((base) + boffs[(nh) * 2 + n_][1]);         \
    }                                                                            \
} while (0)

#define MFMA16(mh, nh) do {                                                      \
    _Pragma("unroll")                                                            \
    for (int ks_ = 0; ks_ < 2; ++ks_)                                            \
    _Pragma("unroll")                                                            \
    for (int m_ = 0; m_ < 4; ++m_)                                               \
    _Pragma("unroll")                                                            \
    for (int n_ = 0; n_ < 2; ++n_)                                               \
        acc[(mh) * 4 + m_][(nh) * 2 + n_] = __builtin_amdgcn_mfma_f32_16x16x32_bf16( \
            avc[m_][ks_], bvc[n_][ks_], acc[(mh) * 4 + m_][(nh) * 2 + n_], 0, 0, 0); \
} while (0)

    const int nt = K >> 6;

    // prologue: stage tile 0; gate A0,B0 (oldest 4 of 8) then enter loop
    STAGEA(0, 0, 0); STAGEB(0, 0, 0); STAGEA(1, 0, 0); STAGEB(1, 0, 0);
    VMWAIT4; BAR();

    int t = 0;
    for (; t < nt - 1; ++t) {
        const int p = t & 1;
        const char* bA = ldsv + p * 32768;
        const char* bB = ldsv + 65536 + p * 32768;
        const int kn = (t + 1) << 6;
        // ph1: reads A0,B0 (valid); stage A0(t+1); gate A1 for ph2
        READA(0, bA); READB(0, bB);
        STAGEA(0, kn, p ^ 1);
        LGKM8;
        BAR();
        PRIO1; MFMA16(0, 0); PRIO0;
        VMWAIT4; BAR();
        // ph2: reads A1; stage B0(t+1); gate B1 for ph3
        READA(1, bA);
        STAGEB(0, kn, p ^ 1);
        BAR();
        PRIO1; MFMA16(1, 0); PRIO0;
        VMWAIT4; BAR();
        // ph3: reads B1; stage A1(t+1); no gate (ph4 re-reads A0)
        READB(1, bB);
        STAGEA(1, kn, p ^ 1);
        BAR();
        PRIO1; MFMA16(1, 1); PRIO0;
        BAR();
        // ph4: reads A0; stage B1(t+1); gate A0,B0(t+1) for next ph1
        READA(0, bA);
        STAGEB(1, kn, p ^ 1);
        BAR();
        PRIO1; MFMA16(0, 1); PRIO0;
        VMWAIT4; BAR();
    }
    // last tile: no staging; drain 2/0
    {
        const int p = t & 1;
        const char* bA = ldsv + p * 32768;
        const char* bB = ldsv + 65536 + p * 32768;
        READA(0, bA); READB(0, bB);
        LGKM8;
        BAR();
        PRIO1; MFMA16(0, 0); PRIO0;
        VMWAIT2; BAR();
        READA(1, bA);
        BAR();
        PRIO1; MFMA16(1, 0); PRIO0;
        VMWAIT0; BAR();
        READB(1, bB);
        BAR();
        PRIO1; MFMA16(1, 1); PRIO0;
        BAR();
        READA(0, bA);
        PRIO1; MFMA16(0, 1); PRIO0;
    }

#pragma unroll
    for (int n = 0; n < 4; ++n) {
        const int col = col0 + n * 64 + wc * 16 + l15;
        const float bz = d.bias[col];
#pragma unroll
        for (int m = 0; m < 8; ++m) {
#pragma unroll
            for (int rg = 0; rg < 4; ++rg) {
                int row = row0 + m * 32 + wr * 16 + l4 * 4 + rg;
                float x = acc[m][n][rg] + bz;
                if (RELU) x = fmaxf(x, 0.f);
                if (OUT == 0) ((u16*)d.C)[(size_t)row * d.ldc + col] = f2b(x);
                else          ((float*)d.C)[(size_t)row * d.ldc + col] = x;
            }
        }
    }
#undef STAGEA
#undef STAGEB
#undef READA
#undef READB
#undef MFMA16
}

// ---------------------------------------------------------------------------
// cand_k: per row (b,i), 256-bit candidate mask of j with mask && sim>=THRESH.
// ---------------------------------------------------------------------------
__global__ __launch_bounds__(256) void cand_k(
    const float* __restrict__ sim, const int* __restrict__ mask,
    u64* __restrict__ cand, int* __restrict__ midx,
    float* __restrict__ osp, float* __restrict__ zb)
{
    const int row = blockIdx.x, j = threadIdx.x;
    size_t off = (size_t)row * Nn + j;
    bool p = mask[off] && (sim[off] >= THRESH);
    u64 bal = __ballot(p);
    if ((j & 63) == 0) cand[row * 4 + (j >> 6)] = bal;
    if (j == 0) midx[row] = -1;
    if (j < SDIM) osp[(size_t)row * SDIM + j] = 0.f;
    if (row == 0) zb[j] = 0.f;
}

// ---------------------------------------------------------------------------
// matchseq_k: sequential greedy match, 1 wave per batch, no block barriers.
// ---------------------------------------------------------------------------
__global__ __launch_bounds__(64) void matchseq_k(
    const float* __restrict__ sim, const u64* __restrict__ cand,
    const float* __restrict__ psp, int* __restrict__ midx,
    float* __restrict__ osp)
{
    const int b = blockIdx.x;
    const int lane = threadIdx.x;
    __shared__ u64 cl[Nn * 4];
    for (int k = lane; k < Nn * 4; k += 64) cl[k] = cand[b * Nn * 4 + k];
    u64 vis = 0;   // meaningful on lanes 0..3 (word = lane)
    for (int i = 0; i < Nn; ++i) {
        u64 c = (lane < 4) ? (cl[i * 4 + lane] & ~vis) : 0ull;
        if (!__any(c != 0ull)) continue;
        u64 cw = __shfl(c, lane >> 4, 64);
        int basebit = (lane & 15) * 4;
        float best = -INFINITY; int bidx = Nn;
        const float* srow = sim + ((size_t)b * Nn + i) * Nn;
#pragma unroll
        for (int k = 0; k < 4; ++k) {
            if ((cw >> (basebit + k)) & 1ull) {
                int j = (lane >> 4) * 64 + basebit + k;
                float v = srow[j];
                if (v > best || (v == best && j < bidx)) { best = v; bidx = j; }
            }
        }
        for (int o = 32; o; o >>= 1) {
            float v2 = __shfl_down(best, o, 64);
            int i2 = __shfl_down(bidx, o, 64);
            if (v2 > best || (v2 == best && i2 < bidx)) { best = v2; bidx = i2; }
        }
        int jstar = __shfl(bidx, 0, 64);
        if (lane == (jstar >> 6)) vis |= 1ull << (jstar & 63);
        if (lane == 0) midx[b * Nn + i] = jstar;
        if (lane < SDIM)
            osp[((size_t)b * Nn + i) * SDIM + lane] = psp[((size_t)b * Nn + jstar) * SDIM + lane];
    }
}

// ---------------------------------------------------------------------------
// ln2_k: paired LayerNorm (img & pc) -> bf16 visb halves. grid (Mrows, 2).
// ---------------------------------------------------------------------------
__global__ __launch_bounds__(256) void ln2_k(
    const float* __restrict__ Xi, const float* __restrict__ gi, const float* __restrict__ bi,
    const float* __restrict__ Xp, const float* __restrict__ gp, const float* __restrict__ bp,
    u16* __restrict__ out)
{
    const int row = blockIdx.x, t = threadIdx.x;
    const float* X = blockIdx.y ? Xp : Xi;
    const float* g = blockIdx.y ? gp : gi;
    const float* be = blockIdx.y ? bp : bi;
    const int ooff = blockIdx.y ? VDIM : 0;
    float4 v = *(const float4*)(X + (size_t)row * VDIM + t * 4);
    float s = v.x + v.y + v.z + v.w;
    __shared__ float l4[4];
    for (int o = 32; o; o >>= 1) s += __shfl_down(s, o, 64);
    if ((t & 63) == 0) l4[t >> 6] = s;
    __syncthreads();
    float mean = (l4[0] + l4[1] + l4[2] + l4[3]) * (1.f / VDIM);
    __syncthreads();
    float dx = v.x - mean, dy = v.y - mean, dz = v.z - mean, dw = v.w - mean;
    float qv = dx * dx + dy * dy + dz * dz + dw * dw;
    for (int o = 32; o; o >>= 1) qv += __shfl_down(qv, o, 64);
    if ((t & 63) == 0) l4[t >> 6] = qv;
    __syncthreads();
    float var = (l4[0] + l4[1] + l4[2] + l4[3]) * (1.f / VDIM);
    float rstd = rsqrtf(var + LNEPS);
    float4 gv = *(const float4*)(g + t * 4);
    float4 bv = *(const float4*)(be + t * 4);
    *(ushort4*)(out + (size_t)row * 2048 + ooff + t * 4) = make_ushort4(
        f2b(dx * rstd * gv.x + bv.x), f2b(dy * rstd * gv.y + bv.y),
        f2b(dz * rstd * gv.z + bv.z), f2b(dw * rstd * gv.w + bv.w));
}

// final LN (fp32 out)
__global__ __launch_bounds__(256) void lnf_k(
    const float* __restrict__ X, const float* __restrict__ g,
    const float* __restrict__ be, float* __restrict__ out)
{
    const int row = blockIdx.x, t = threadIdx.x;
    float4 v = *(const float4*)(X + (size_t)row * VDIM + t * 4);
    float s = v.x + v.y + v.z + v.w;
    __shared__ float l4[4];
    for (int o = 32; o; o >>= 1) s += __shfl_down(s, o, 64);
    if ((t & 63) == 0) l4[t >> 6] = s;
    __syncthreads();
    float mean = (l4[0] + l4[1] + l4[2] + l4[3]) * (1.f / VDIM);
    __syncthreads();
    float dx = v.x - mean, dy = v.y - mean, dz = v.z - mean, dw = v.w - mean;
    float qv = dx * dx + dy * dy + dz * dz + dw * dw;
    for (int o = 32; o; o >>= 1) qv += __shfl_down(qv, o, 64);
    if ((t & 63) == 0) l4[t >> 6] = qv;
    __syncthreads();
    float var = (l4[0] + l4[1] + l4[2] + l4[3]) * (1.f / VDIM);
    float rstd = rsqrtf(var + LNEPS);
    float4 gv = *(const float4*)(g + t * 4);
    float4 bv = *(const float4*)(be + t * 4);
    *(float4*)(out + (size_t)row * VDIM + t * 4) = make_float4(
        dx * rstd * gv.x + bv.x, dy * rstd * gv.y + bv.y,
        dz * rstd * gv.z + bv.z, dw * rstd * gv.w + bv.w);
}

// ---------------------------------------------------------------------------
extern "C" void kernel_launch(void* const* d_in, const int* in_sizes, int n_in,
                              void* d_out, int out_size, void* d_ws, size_t ws_size,
                              hipStream_t stream)
{
    const float* image  = (const float*)d_in[0];
    const float* pcf    = (const float*)d_in[1];
    const float* pimage = (const float*)d_in[2];
    const float* ppcf   = (const float*)d_in[3];
    const float* psp    = (const float*)d_in[4];
    const int*   mask   = (const int*)d_in[5];
    const float* iw1 = (const float*)d_in[6];  const float* ib1 = (const float*)d_in[7];
    const float* iw2 = (const float*)d_in[8];  const float* ib2 = (const float*)d_in[9];
    const float* iw3 = (const float*)d_in[10]; const float* ib3 = (const float*)d_in[11];
    const float* ig  = (const float*)d_in[12]; const float* ibeta = (const float*)d_in[13];
    const float* pw1 = (const float*)d_in[14]; const float* pb1 = (const float*)d_in[15];
    const float* pw2 = (const float*)d_in[16]; const float* pb2 = (const float*)d_in[17];
    const float* pw3 = (const float*)d_in[18]; const float* pb3 = (const float*)d_in[19];
    const float* pg  = (const float*)d_in[20]; const float* pbeta = (const float*)d_in[21];
    const float* fw1 = (const float*)d_in[22]; const float* fb1 = (const float*)d_in[23];
    const float* fw2 = (const float*)d_in[24]; const float* fb2 = (const float*)d_in[25];
    const float* fg  = (const float*)d_in[26]; const float* fbeta = (const float*)d_in[27];

    float* out_vis = (float*)d_out;                        // [8192][1024]
    float* out_sp  = (float*)d_out + (size_t)Mrows * VDIM; // [8192][8]

    // ---- workspace carve (200.7 MB; lifetime-checked) ----
    char* wsb = (char*)d_ws;
    float* nf   = (float*)(wsb + 0);        // pack->sim; reused as zbuf after
    float* np_  = (float*)(wsb + 32768);
    int*   midx = (int*)(wsb + 65536);
    u64*   cand = (u64*)(wsb + 98304);      // 8192*4 u64 = 256 KB
    u16*   wt0  = (u16*)(wsb + 524288);     // weights region, 40.76 MB
    u16* iw1t = wt0;
    u16* iw2t = wt0 + 8388608;
    u16* iw3t = wt0 + 12582912;
    u16* pw1t = wt0 + 14680064;
    u16* pw2t = wt0 + 15859712;
    u16* pw3t = wt0 + 16449536;
    u16* fw1t = wt0 + 17235968;
    u16* fw2t = wt0 + 19333120;
    char* R1 = wsb + 41287680;   // 46.14 MB: featb; then h2b(@0)+ph2b(@32M)
    char* R2 = wsb + 87425024;   // 46.14 MB: pfeatb; then preLNimg(@0)
    char* R3 = wsb + 133562368;  // 33.55 MB: sim; h1b; visb; preLNf
    char* R4 = wsb + 167116800;  // 33.55 MB: ph1b; preLNpc; fh1b

    u16*   featb   = (u16*)R1;
    u16*   pfeatb  = (u16*)R2;
    float* sim     = (float*)R3;
    u16*   h1b     = (u16*)R3;
    u16*   ph1b    = (u16*)R4;
    u16*   h2b     = (u16*)R1;
    u16*   ph2b    = (u16*)(R1 + 33554432);
    float* preLNimg = (float*)R2;
    float* preLNpc  = (float*)R4;
    u16*   visb    = (u16*)R3;
    u16*   fh1b    = (u16*)R4;
    float* preLNf  = (float*)R3;
    float* zbuf    = nf;

    // 1. pack + norms
    pack_k<<<dim3(Mrows, 2), 256, 0, stream>>>(image, pcf, pimage, ppcf,
                                               featb, pfeatb, nf, np_);
    // 2. all weight transposes (one launch)
    {
        TD t0 = { iw1, iw1t, 2 * IDIM, IDIM, 0 };      // 8192
        TD t1 = { iw2, iw2t, IDIM, IDIM, 8192 };       // 4096
        TD t2 = { iw3, iw3t, IDIM, VDIM, 12288 };      // 2048
        TD t3 = { pw1, pw1t, 2 * PDIM, PDIM, 14336 };  // 1152
        TD t4 = { pw2, pw2t, PDIM, PDIM, 15488 };      // 576
        TD t5 = { pw3, pw3t, PDIM, VDIM, 16064 };      // 768
        TD t6 = { fw1, fw1t, 2048, VDIM, 16832 };      // 2048
        TD t7 = { fw2, fw2t, VDIM, VDIM, 18880 };      // 1024 -> 19904
        twtg_k<<<dim3(19904), 256, 0, stream>>>(t0, t1, t2, t3, t4, t5, t6, t7);
    }
    // 3. similarity
    simmm_k<<<dim3(2, 64), 256, 0, stream>>>(featb, pfeatb, nf, np_, sim);
    // 4. candidate masks (+ defaults + zbuf)
    cand_k<<<dim3(Mrows), 256, 0, stream>>>(sim, mask, cand, midx, out_sp, zbuf);
    // 5. sequential greedy match (1 wave per batch)
    matchseq_k<<<dim3(Bn), 64, 0, stream>>>(sim, cand, psp, midx, out_sp);

    // 6. depth-1: img1 + pc1 grouped
    {
        MMDesc di = { featb, pfeatb, (const u16*)zbuf, midx, iw1t, ib1, h1b,
                      D2, 0, IDIM, 2 * IDIM, IDIM, 256 };
        MMDesc dp = { featb, pfeatb, (const u16*)zbuf, midx, pw1t, pb1, ph1b,
                      D2, IDIM, PDIM, 2 * PDIM, PDIM, 96 };
        mmg_k<1, 1, 0><<<dim3(352), 512, 0, stream>>>(di, dp, 256);
    }
    // 7. depth-2: img2 + pc2 grouped
    {
        MMDesc di = { h1b, nullptr, nullptr, nullptr, iw2t, ib2, h2b,
                      IDIM, 0, 0, IDIM, IDIM, 256 };
        MMDesc dp = { ph1b, nullptr, nullptr, nullptr, pw2t, pb2, ph2b,
                      PDIM, 0, 0, PDIM, PDIM, 96 };
        mmg_k<0, 0, 0><<<dim3(352), 512, 0, stream>>>(di, dp, 256);
    }
    // 8. depth-3: img3 + pc3 grouped (fp32 out)
    {
        MMDesc di = { h2b, nullptr, nullptr, nullptr, iw3t, ib3, preLNimg,
                      IDIM, 0, 0, IDIM, VDIM, 128 };
        MMDesc dp = { ph2b, nullptr, nullptr, nullptr, pw3t, pb3, preLNpc,
                      PDIM, 0, 0, PDIM, VDIM, 128 };
        mmg_k<0, 0, 1><<<dim3(256), 512, 0, stream>>>(di, dp, 128);
    }
    // 9. paired LN -> visb
    ln2_k<<<dim3(Mrows, 2), 256, 0, stream>>>(preLNimg, ig, ibeta,
                                              preLNpc, pg, pbeta, visb);
    // 10. fused branch
    {
        MMDesc df = { visb, nullptr, nullptr, nullptr, fw1t, fb1, fh1b,
                      2048, 0, 0, 2048, VDIM, 128 };
        mmg_k<0, 1, 0><<<dim3(128), 512, 0, stream>>>(df, df, 128);
    }
    {
        MMDesc df = { fh1b, nullptr, nullptr, nullptr, fw2t, fb2, preLNf,
                      VDIM, 0, 0, VDIM, VDIM, 128 };
        mmg_k<0, 0, 1><<<dim3(128), 512, 0, stream>>>(df, df, 128);
    }
    lnf_k<<<dim3(Mrows), 256, 0, stream>>>(preLNf, fg, fbeta, out_vis);
}